// Round 1
// baseline (5667.128 us; speedup 1.0000x reference)
//
#include <hip/hip_runtime.h>
#include <math.h>

#define NB   4096
#define LL   50
#define FF   128
#define HH   8
#define DQKn 128
#define DVn  16

// LDS layout (floats):
//   [0,      6600)  sq  (stride 132)  -- first 6400 doubles as sx during staging/QKV,
//                                        and as satt [50][64] after scores
//   [6600,  13000)  sk  (stride 128)
//   [13000, 13800)  sv  [50][16]
#define SQ_STRIDE 132
#define OFF_SK 6600
#define OFF_SV 13000
#define LDS_FLOATS 13800   // 55.2 KB -> 2 blocks/CU

__global__ __launch_bounds__(256, 2)
void attn_fused(const float* __restrict__ hid,
                const float* __restrict__ Wq, const float* __restrict__ bq,
                const float* __restrict__ Wk, const float* __restrict__ bk,
                const float* __restrict__ Wv, const float* __restrict__ bv,
                float* __restrict__ out)
{
    __shared__ __align__(16) float lds[LDS_FLOATS];
    float* sx   = lds;            // [50][128]
    float* sq   = lds;            // [50][132] (overlays sx after QKV regs done)
    float* sk   = lds + OFF_SK;   // [50][128]
    float* sv   = lds + OFF_SV;   // [50][16]
    float* satt = lds;            // [50][64]  (overlays sq after scores)

    const int t  = threadIdx.x;
    const int bh = blockIdx.x;
    const int b  = bh >> 3;       // b-major: 8 head-blocks of same b adjacent -> x_b L2/L3 reuse
    const int h  = bh & 7;

    // ---- stage x[b] -> LDS (1600 float4, coalesced) ----
    {
        const float4* src = (const float4*)(hid + (size_t)b * (LL*FF));
        float4* dst = (float4*)sx;
        #pragma unroll
        for (int r = 0; r < 7; ++r) {
            int idx = t + r*256;
            if (idx < 1600) dst[idx] = src[idx];
        }
    }
    __syncthreads();

    // ---- Q/K/V projections, fp32 FMA, accumulators in registers ----
    const int lane32 = t & 31;
    const int grp    = t >> 5;        // 0..7 ; rows l = grp + 8*i (balanced 6-7 rows/group)
    const int e0     = lane32 * 4;    // e-quad
    const int dv     = t & 15;
    const int mrow0  = t >> 4;        // V rows m = mrow0 + 16*p

    float4 accq[7], acck[7];
    {
        float4 bqv = *(const float4*)(bq + h*DQKn + e0);
        float4 bkv = *(const float4*)(bk + h*DQKn + e0);
        #pragma unroll
        for (int i = 0; i < 7; ++i) { accq[i] = bqv; acck[i] = bkv; }
    }
    float accv[4];
    {
        float bvv = bv[h*DVn + dv];
        #pragma unroll
        for (int p = 0; p < 4; ++p) accv[p] = bvv;
    }

    const float* wqp = Wq + (size_t)h*FF*DQKn + e0;
    const float* wkp = Wk + (size_t)h*FF*DQKn + e0;
    const float* wvp = Wv + (size_t)h*FF*DVn + dv;

    for (int f4 = 0; f4 < FF; f4 += 4) {
        float4 xq[7];                              // b128 LDS broadcasts (2 addrs/wave: free)
        #pragma unroll
        for (int i = 0; i < 7; ++i) {
            int l  = grp + 8*i;
            int lr = (l < LL) ? l : 0;
            xq[i] = *(const float4*)(sx + lr*FF + f4);
        }
        float4 xv4[4];
        #pragma unroll
        for (int p = 0; p < 4; ++p) {
            int m  = mrow0 + 16*p;
            int mr = (m < LL) ? m : 0;
            xv4[p] = *(const float4*)(sx + mr*FF + f4);
        }
        #pragma unroll
        for (int ff = 0; ff < 4; ++ff) {
            float4 wq4 = *(const float4*)(wqp + (size_t)(f4+ff)*DQKn);
            float4 wk4 = *(const float4*)(wkp + (size_t)(f4+ff)*DQKn);
            float  wvv = wvp[(size_t)(f4+ff)*DVn];
            #pragma unroll
            for (int i = 0; i < 7; ++i) {
                float xs = (&xq[i].x)[ff];
                accq[i].x += xs*wq4.x; accq[i].y += xs*wq4.y;
                accq[i].z += xs*wq4.z; accq[i].w += xs*wq4.w;
                acck[i].x += xs*wk4.x; acck[i].y += xs*wk4.y;
                acck[i].z += xs*wk4.z; acck[i].w += xs*wk4.w;
            }
            #pragma unroll
            for (int p = 0; p < 4; ++p) {
                float xs = (&xv4[p].x)[ff];
                accv[p] += xs * wvv;
            }
        }
    }
    __syncthreads();   // all sx reads complete before sq overlays it

    #pragma unroll
    for (int i = 0; i < 7; ++i) {
        int l = grp + 8*i;
        if (l < LL) {
            *(float4*)(sq + l*SQ_STRIDE + e0) = accq[i];
            *(float4*)(sk + l*FF        + e0) = acck[i];
        }
    }
    #pragma unroll
    for (int p = 0; p < 4; ++p) {
        int m = mrow0 + 16*p;
        if (m < LL) sv[m*DVn + dv] = accv[p];
    }
    __syncthreads();

    // ---- scores = leaky(Q K^T), softmax over l (column axis) via wave shuffles ----
    const int lane  = t & 63;                 // = query row l
    const int wid   = t >> 6;                 // wave 0..3 owns columns m = wid + 4*j
    const int lrow  = (lane < LL) ? lane : (LL-1);
    const int ncols = (wid < 2) ? 13 : 12;

    float acc[13];
    #pragma unroll
    for (int j = 0; j < 13; ++j) acc[j] = 0.f;

    for (int e4 = 0; e4 < DQKn; e4 += 4) {
        float4 q4 = *(const float4*)(sq + lrow*SQ_STRIDE + e4);   // stride 132: bank-spread
        #pragma unroll
        for (int j = 0; j < 13; ++j) {
            if (j < ncols) {
                int m = wid + 4*j;
                float4 k4 = *(const float4*)(sk + m*FF + e4);     // wave-broadcast
                acc[j] += q4.x*k4.x + q4.y*k4.y + q4.z*k4.z + q4.w*k4.w;
            }
        }
    }

    float att[13];
    #pragma unroll
    for (int j = 0; j < 13; ++j) {
        if (j < ncols) {
            float s = acc[j];
            s = (s > 0.f) ? s : 0.1f*s;          // leaky_relu(0.1) BEFORE softmax
            if (lane >= LL) s = -INFINITY;       // mask pad rows
            float mx = s;
            #pragma unroll
            for (int off = 32; off > 0; off >>= 1)
                mx = fmaxf(mx, __shfl_xor(mx, off));
            float p = __expf(s - mx);            // -inf lanes -> 0
            float sum = p;
            #pragma unroll
            for (int off = 32; off > 0; off >>= 1)
                sum += __shfl_xor(sum, off);
            att[j] = p / sum;
        }
    }

    __syncthreads();   // everyone done reading sq; reuse region for satt
    #pragma unroll
    for (int j = 0; j < 13; ++j)
        if (j < ncols) satt[(wid + 4*j)*64 + lane] = att[j];
    __syncthreads();

    // ---- out[l, h*16+v] = relu( sum_m att[l][m] * V[m][v] ) ----
    const int lo = t >> 2;            // 0..63 (50 valid)
    const int v0 = (t & 3) * 4;
    if (lo < LL) {
        float4 o = make_float4(0.f, 0.f, 0.f, 0.f);
        for (int m = 0; m < LL; ++m) {
            float  a  = satt[m*64 + lo];
            float4 vv = *(const float4*)(sv + m*DVn + v0);
            o.x += a*vv.x; o.y += a*vv.y; o.z += a*vv.z; o.w += a*vv.w;
        }
        o.x = fmaxf(o.x, 0.f); o.y = fmaxf(o.y, 0.f);
        o.z = fmaxf(o.z, 0.f); o.w = fmaxf(o.w, 0.f);
        *(float4*)(out + (size_t)b*(LL*FF) + lo*FF + h*DVn + v0) = o;
    }
}

extern "C" void kernel_launch(void* const* d_in, const int* in_sizes, int n_in,
                              void* d_out, int out_size, void* d_ws, size_t ws_size,
                              hipStream_t stream)
{
    const float* hid = (const float*)d_in[0];
    const float* Wq  = (const float*)d_in[1];
    const float* bq  = (const float*)d_in[2];
    const float* Wk  = (const float*)d_in[3];
    const float* bk  = (const float*)d_in[4];
    const float* Wv  = (const float*)d_in[5];
    const float* bv  = (const float*)d_in[6];
    float* o = (float*)d_out;

    attn_fused<<<dim3(NB*HH), dim3(256), 0, stream>>>(hid, Wq, bq, Wk, bk, Wv, bv, o);
}

// Round 2
// 1700.186 us; speedup vs baseline: 3.3332x; 3.3332x over previous
//
#include <hip/hip_runtime.h>
#include <math.h>

#define NB   4096
#define LL   50
#define FF   128
#define HH   8
#define DQKn 128
#define DVn  16
#define NT   17        // 8 Q-tiles + 8 K-tiles + 1 V-tile (N=16 each)
#define XSTR 136       // padded bf16 row stride for x (136*2B = 272B, 16B-aligned, 2-way banks)

typedef __attribute__((ext_vector_type(8))) short bf16x8;
typedef __attribute__((ext_vector_type(4))) float f32x4;

__device__ __forceinline__ ushort bf_hi(float x) {
    uint u = __float_as_uint(x);
    uint r = u + 0x7FFFu + ((u >> 16) & 1u);   // RTNE to bf16
    return (ushort)(r >> 16);
}
__device__ __forceinline__ float bf_f(ushort b) { return __uint_as_float(((uint)b) << 16); }

// ---------------- weight pre-pack: fragment-major bf16 hi/lo -----------------
// layout: [h][tile 0..16][ks 0..3][part hi/lo][lane 0..63][8 bf16]
//   B[k][n]: n = lane&15, k = (lane>>4)*8 + j ; f = ks*32 + k ; e = tile_e + n
__global__ void pack_w(const float* __restrict__ Wq, const float* __restrict__ Wk,
                       const float* __restrict__ Wv, ushort* __restrict__ wp)
{
    int id = blockIdx.x * 256 + threadIdx.x;          // 8*17*4*64 = 34816 threads
    if (id >= HH*NT*4*64) return;
    int lane = id & 63;
    int ks   = (id >> 6) & 3;
    int ht   = id >> 8;                               // 0..135
    int t    = ht % NT;
    int h    = ht / NT;
    int c    = lane & 15;
    int f0   = ks*32 + (lane >> 4)*8;
    const float* src; int e, ncols;
    if (t < 8)       { src = Wq + (size_t)h*FF*DQKn; e = t*16 + c;       ncols = DQKn; }
    else if (t < 16) { src = Wk + (size_t)h*FF*DQKn; e = (t-8)*16 + c;   ncols = DQKn; }
    else             { src = Wv + (size_t)h*FF*DVn;  e = c;              ncols = DVn;  }
    ushort hi[8], lo[8];
    #pragma unroll
    for (int j = 0; j < 8; ++j) {
        float x = src[(size_t)(f0 + j)*ncols + e];
        ushort hb = bf_hi(x);
        hi[j] = hb;
        lo[j] = bf_hi(x - bf_f(hb));
    }
    size_t base = ((((size_t)(h*NT + t)*4 + ks)*2 + 0)*64 + lane)*8;
    *(ushort4*)(wp + base)       = make_ushort4(hi[0],hi[1],hi[2],hi[3]);
    *(ushort4*)(wp + base + 4)   = make_ushort4(hi[4],hi[5],hi[6],hi[7]);
    *(ushort4*)(wp + base + 512) = make_ushort4(lo[0],lo[1],lo[2],lo[3]);  // part=1 is +64*8
    *(ushort4*)(wp + base + 516) = make_ushort4(lo[4],lo[5],lo[6],lo[7]);
}

// ---------------- fused attention, MFMA projections ----------------
// LDS phases (13800 floats = 55.2 KB -> 2 blocks/CU):
//   phase A: xhi[64][136] bf16 @ushort 0, xlo @ushort 8704   (34816 B)
//   phase B: sq[50][132] @float 0 (overlays x), sk @6600, sv @13000
//   phase C: satt[50][64] @float 0 (overlays sq)
#define SQ_STRIDE 132
#define OFF_SK 6600
#define OFF_SV 13000
#define LDS_FLOATS 13800

__global__ __launch_bounds__(256, 2)
void attn_fused(const float* __restrict__ hid, const ushort* __restrict__ wp,
                const float* __restrict__ bq, const float* __restrict__ bk,
                const float* __restrict__ bv, float* __restrict__ out)
{
    __shared__ __align__(16) float lds[LDS_FLOATS];
    ushort* xhi = (ushort*)lds;
    ushort* xlo = xhi + 64*XSTR;
    float* sq   = lds;
    float* sk   = lds + OFF_SK;
    float* sv   = lds + OFF_SV;
    float* satt = lds;

    const int t    = threadIdx.x;
    const int b    = blockIdx.x >> 3;
    const int h    = blockIdx.x & 7;
    const int lane = t & 63;
    const int w    = t >> 6;          // wave 0..3
    const int c16  = lane & 15;
    const int quad = lane >> 4;       // 0..3

    // ---- stage x -> bf16 hi/lo in LDS ----
    {
        const float4* src = (const float4*)(hid + (size_t)b * (LL*FF));
        for (int i = t; i < 1600; i += 256) {
            float4 v = src[i];
            int l = i >> 5, f = (i & 31) * 4;
            ushort4 hv, lv;
            hv.x = bf_hi(v.x); lv.x = bf_hi(v.x - bf_f(hv.x));
            hv.y = bf_hi(v.y); lv.y = bf_hi(v.y - bf_f(hv.y));
            hv.z = bf_hi(v.z); lv.z = bf_hi(v.z - bf_f(hv.z));
            hv.w = bf_hi(v.w); lv.w = bf_hi(v.w - bf_f(hv.w));
            *(ushort4*)(xhi + l*XSTR + f) = hv;
            *(ushort4*)(xlo + l*XSTR + f) = lv;
        }
        // zero pad rows 50..63 (avoid garbage feeding MFMA)
        for (int i = t; i < 476; i += 256) {
            ushort* dst = (i < 238 ? xhi : xlo) + 50*XSTR + (i % 238) * 8;
            *(ushort4*)(dst)     = make_ushort4(0,0,0,0);
            *(ushort4*)(dst + 4) = make_ushort4(0,0,0,0);
        }
    }
    __syncthreads();

    // ---- projections: bf16x3 MFMA. Wave w owns Q e[32w,32w+32), K same, V M-tile w ----
    f32x4 aQ[4][2], aK[4][2], aV;
    #pragma unroll
    for (int m = 0; m < 4; ++m)
        #pragma unroll
        for (int nt = 0; nt < 2; ++nt) {
            aQ[m][nt] = (f32x4){0.f,0.f,0.f,0.f};
            aK[m][nt] = (f32x4){0.f,0.f,0.f,0.f};
        }
    aV = (f32x4){0.f,0.f,0.f,0.f};

    const ushort* wbase = wp + (size_t)h*NT*4096 + lane*8;   // tile stride 4096, ks stride 1024, part stride 512
    #define FRG(tt,kk,pp) (*(const bf16x8*)(wbase + (size_t)(tt)*4096 + (kk)*1024 + (pp)*512))

    for (int ks = 0; ks < 4; ++ks) {
        bf16x8 q0h = FRG(2*w,   ks, 0), q0l = FRG(2*w,   ks, 1);
        bf16x8 q1h = FRG(2*w+1, ks, 0), q1l = FRG(2*w+1, ks, 1);
        bf16x8 k0h = FRG(8+2*w,   ks, 0), k0l = FRG(8+2*w,   ks, 1);
        bf16x8 k1h = FRG(8+2*w+1, ks, 0), k1l = FRG(8+2*w+1, ks, 1);
        bf16x8 vth = FRG(16, ks, 0),      vtl = FRG(16, ks, 1);
        #pragma unroll
        for (int m = 0; m < 4; ++m) {
            const ushort* xp = xhi + (m*16 + c16)*XSTR + ks*32 + quad*8;
            bf16x8 ah = *(const bf16x8*)xp;
            bf16x8 al = *(const bf16x8*)(xp + 64*XSTR);
            aQ[m][0] = __builtin_amdgcn_mfma_f32_16x16x32_bf16(ah, q0h, aQ[m][0], 0,0,0);
            aQ[m][0] = __builtin_amdgcn_mfma_f32_16x16x32_bf16(ah, q0l, aQ[m][0], 0,0,0);
            aQ[m][0] = __builtin_amdgcn_mfma_f32_16x16x32_bf16(al, q0h, aQ[m][0], 0,0,0);
            aQ[m][1] = __builtin_amdgcn_mfma_f32_16x16x32_bf16(ah, q1h, aQ[m][1], 0,0,0);
            aQ[m][1] = __builtin_amdgcn_mfma_f32_16x16x32_bf16(ah, q1l, aQ[m][1], 0,0,0);
            aQ[m][1] = __builtin_amdgcn_mfma_f32_16x16x32_bf16(al, q1h, aQ[m][1], 0,0,0);
            aK[m][0] = __builtin_amdgcn_mfma_f32_16x16x32_bf16(ah, k0h, aK[m][0], 0,0,0);
            aK[m][0] = __builtin_amdgcn_mfma_f32_16x16x32_bf16(ah, k0l, aK[m][0], 0,0,0);
            aK[m][0] = __builtin_amdgcn_mfma_f32_16x16x32_bf16(al, k0h, aK[m][0], 0,0,0);
            aK[m][1] = __builtin_amdgcn_mfma_f32_16x16x32_bf16(ah, k1h, aK[m][1], 0,0,0);
            aK[m][1] = __builtin_amdgcn_mfma_f32_16x16x32_bf16(ah, k1l, aK[m][1], 0,0,0);
            aK[m][1] = __builtin_amdgcn_mfma_f32_16x16x32_bf16(al, k1h, aK[m][1], 0,0,0);
            if (m == w) {   // wave-uniform
                aV = __builtin_amdgcn_mfma_f32_16x16x32_bf16(ah, vth, aV, 0,0,0);
                aV = __builtin_amdgcn_mfma_f32_16x16x32_bf16(ah, vtl, aV, 0,0,0);
                aV = __builtin_amdgcn_mfma_f32_16x16x32_bf16(al, vth, aV, 0,0,0);
            }
        }
    }
    __syncthreads();   // all x reads done; sq/sk overlay x region

    // ---- epilogue: bias add, C-layout (col=lane&15, row=quad*4+r) -> fp32 LDS ----
    #pragma unroll
    for (int m = 0; m < 4; ++m) {
        #pragma unroll
        for (int nt = 0; nt < 2; ++nt) {
            int e = w*32 + nt*16 + c16;
            float bQ = bq[h*DQKn + e];
            float bK = bk[h*DQKn + e];
            #pragma unroll
            for (int r = 0; r < 4; ++r) {
                int l = m*16 + quad*4 + r;
                if (l < LL) {
                    sq[l*SQ_STRIDE + e] = aQ[m][nt][r] + bQ;
                    sk[l*FF        + e] = aK[m][nt][r] + bK;
                }
            }
        }
    }
    {
        float bV = bv[h*DVn + c16];
        #pragma unroll
        for (int r = 0; r < 4; ++r) {
            int mrow = w*16 + quad*4 + r;
            if (mrow < LL) sv[mrow*DVn + c16] = aV[r] + bV;
        }
    }
    __syncthreads();

    // ---- scores = leaky(Q K^T), softmax over l (column axis) via wave shuffles ----
    const int wid   = w;
    const int lrow  = (lane < LL) ? lane : (LL-1);
    const int ncols = (wid < 2) ? 13 : 12;

    float acc[13];
    #pragma unroll
    for (int j = 0; j < 13; ++j) acc[j] = 0.f;

    for (int e4 = 0; e4 < DQKn; e4 += 4) {
        float4 q4 = *(const float4*)(sq + lrow*SQ_STRIDE + e4);
        #pragma unroll
        for (int j = 0; j < 13; ++j) {
            if (j < ncols) {
                int m = wid + 4*j;
                float4 k4 = *(const float4*)(sk + m*FF + e4);
                acc[j] += q4.x*k4.x + q4.y*k4.y + q4.z*k4.z + q4.w*k4.w;
            }
        }
    }

    float att[13];
    #pragma unroll
    for (int j = 0; j < 13; ++j) {
        if (j < ncols) {
            float s = acc[j];
            s = (s > 0.f) ? s : 0.1f*s;          // leaky_relu(0.1)
            if (lane >= LL) s = -INFINITY;
            float mx = s;
            #pragma unroll
            for (int off = 32; off > 0; off >>= 1)
                mx = fmaxf(mx, __shfl_xor(mx, off));
            float p = __expf(s - mx);
            float sum = p;
            #pragma unroll
            for (int off = 32; off > 0; off >>= 1)
                sum += __shfl_xor(sum, off);
            att[j] = p / sum;
        }
    }

    __syncthreads();
    #pragma unroll
    for (int j = 0; j < 13; ++j)
        if (j < ncols) satt[(wid + 4*j)*64 + lane] = att[j];
    __syncthreads();

    // ---- out[l, h*16+v] = relu( sum_m att[l][m] * V[m][v] ) ----
    const int lo = t >> 2;
    const int v0 = (t & 3) * 4;
    if (lo < LL) {
        float4 o = make_float4(0.f, 0.f, 0.f, 0.f);
        for (int m = 0; m < LL; ++m) {
            float  a  = satt[m*64 + lo];
            float4 vv = *(const float4*)(sv + m*DVn + v0);
            o.x += a*vv.x; o.y += a*vv.y; o.z += a*vv.z; o.w += a*vv.w;
        }
        o.x = fmaxf(o.x, 0.f); o.y = fmaxf(o.y, 0.f);
        o.z = fmaxf(o.z, 0.f); o.w = fmaxf(o.w, 0.f);
        *(float4*)(out + (size_t)b*(LL*FF) + lo*FF + h*DVn + v0) = o;
    }
}

extern "C" void kernel_launch(void* const* d_in, const int* in_sizes, int n_in,
                              void* d_out, int out_size, void* d_ws, size_t ws_size,
                              hipStream_t stream)
{
    const float* hid = (const float*)d_in[0];
    const float* Wq  = (const float*)d_in[1];
    const float* bq  = (const float*)d_in[2];
    const float* Wk  = (const float*)d_in[3];
    const float* bk  = (const float*)d_in[4];
    const float* Wv  = (const float*)d_in[5];
    const float* bv  = (const float*)d_in[6];
    float* o    = (float*)d_out;
    ushort* wp  = (ushort*)d_ws;   // 8*17*4*2*64*8 ushorts = 1.06 MiB

    pack_w<<<dim3(136), dim3(256), 0, stream>>>(Wq, Wk, Wv, wp);
    attn_fused<<<dim3(NB*HH), dim3(256), 0, stream>>>(hid, wp, bq, bk, bv, o);
}

// Round 3
// 930.998 us; speedup vs baseline: 6.0872x; 1.8262x over previous
//
#include <hip/hip_runtime.h>
#include <math.h>

#define NB   4096
#define LL   50
#define FF   128
#define HH   8
#define DQKn 128
#define DVn  16
#define NT   17        // 8 Q-tiles + 8 K-tiles + 1 V-tile (N=16 each)
#define XSTR 136       // padded bf16 row stride for x

typedef __attribute__((ext_vector_type(8))) short bf16x8;
typedef __attribute__((ext_vector_type(4))) float f32x4;

__device__ __forceinline__ ushort bf_hi(float x) {
    uint u = __float_as_uint(x);
    uint r = u + 0x7FFFu + ((u >> 16) & 1u);   // RTNE to bf16
    return (ushort)(r >> 16);
}
__device__ __forceinline__ float bf_f(ushort b) { return __uint_as_float(((uint)b) << 16); }

// ---------------- weight pre-pack: fragment-major bf16 hi/lo -----------------
__global__ void pack_w(const float* __restrict__ Wq, const float* __restrict__ Wk,
                       const float* __restrict__ Wv, ushort* __restrict__ wp)
{
    int id = blockIdx.x * 256 + threadIdx.x;          // 8*17*4*64 = 34816 threads
    if (id >= HH*NT*4*64) return;
    int lane = id & 63;
    int ks   = (id >> 6) & 3;
    int ht   = id >> 8;
    int t    = ht % NT;
    int h    = ht / NT;
    int c    = lane & 15;
    int f0   = ks*32 + (lane >> 4)*8;
    const float* src; int e, ncols;
    if (t < 8)       { src = Wq + (size_t)h*FF*DQKn; e = t*16 + c;       ncols = DQKn; }
    else if (t < 16) { src = Wk + (size_t)h*FF*DQKn; e = (t-8)*16 + c;   ncols = DQKn; }
    else             { src = Wv + (size_t)h*FF*DVn;  e = c;              ncols = DVn;  }
    ushort hi[8], lo[8];
    #pragma unroll
    for (int j = 0; j < 8; ++j) {
        float x = src[(size_t)(f0 + j)*ncols + e];
        ushort hb = bf_hi(x);
        hi[j] = hb;
        lo[j] = bf_hi(x - bf_f(hb));
    }
    size_t base = ((((size_t)(h*NT + t)*4 + ks)*2 + 0)*64 + lane)*8;
    *(ushort4*)(wp + base)       = make_ushort4(hi[0],hi[1],hi[2],hi[3]);
    *(ushort4*)(wp + base + 4)   = make_ushort4(hi[4],hi[5],hi[6],hi[7]);
    *(ushort4*)(wp + base + 512) = make_ushort4(lo[0],lo[1],lo[2],lo[3]);
    *(ushort4*)(wp + base + 516) = make_ushort4(lo[4],lo[5],lo[6],lo[7]);
}

// ---------------- fused attention ----------------
// LDS (17184 floats = 68.7 KB -> 2 blocks/CU), phased overlays:
//   A: xhi [64][136] ushort @0, xlo @ushort 8704          (34.8 KB)
//   B: qhi/qlo/khi/klo frag panels @ushort 0/8192/16384/24576 (16 KB each, overlay x)
//      sv fp32 [50][16] @float 16384
//   C: satt fp32 [64][68] @float 0 (overlays q panels)
#define QH_OFF 0
#define QL_OFF 8192
#define KH_OFF 16384
#define KL_OFF 24576
#define SV_OFF 16384      // float index (byte 65536)
#define SATT_STR 68
#define LDS_FLOATS 17184

__global__ __launch_bounds__(256, 2)
void attn_fused(const float* __restrict__ hid, const ushort* __restrict__ wp,
                const float* __restrict__ bq, const float* __restrict__ bk,
                const float* __restrict__ bv, float* __restrict__ out)
{
    __shared__ __align__(16) float lds[LDS_FLOATS];
    ushort* us   = (ushort*)lds;
    ushort* xhi  = us;
    ushort* xlo  = us + 64*XSTR;
    float*  sv   = lds + SV_OFF;
    float*  satt = lds;

    const int t    = threadIdx.x;
    const int b    = blockIdx.x >> 3;
    const int h    = blockIdx.x & 7;
    const int lane = t & 63;
    const int w    = t >> 6;
    const int c16  = lane & 15;
    const int quad = lane >> 4;

    // ---- stage x -> bf16 hi/lo in LDS (pad rows stay garbage: masked later) ----
    {
        const float4* src = (const float4*)(hid + (size_t)b * (LL*FF));
        for (int i = t; i < 1600; i += 256) {
            float4 v = src[i];
            int l = i >> 5, f = (i & 31) * 4;
            ushort4 hv, lv;
            hv.x = bf_hi(v.x); lv.x = bf_hi(v.x - bf_f(hv.x));
            hv.y = bf_hi(v.y); lv.y = bf_hi(v.y - bf_f(hv.y));
            hv.z = bf_hi(v.z); lv.z = bf_hi(v.z - bf_f(hv.z));
            hv.w = bf_hi(v.w); lv.w = bf_hi(v.w - bf_f(hv.w));
            *(ushort4*)(xhi + l*XSTR + f) = hv;
            *(ushort4*)(xlo + l*XSTR + f) = lv;
        }
    }
    __syncthreads();

    // ---- projections: bf16x3 MFMA. Wave w owns Q/K e[32w,32w+32), V M-tile w ----
    f32x4 aQ[4][2], aK[4][2], aV;
    #pragma unroll
    for (int m = 0; m < 4; ++m)
        #pragma unroll
        for (int nt = 0; nt < 2; ++nt) {
            aQ[m][nt] = (f32x4){0.f,0.f,0.f,0.f};
            aK[m][nt] = (f32x4){0.f,0.f,0.f,0.f};
        }
    aV = (f32x4){0.f,0.f,0.f,0.f};

    const ushort* wbase = wp + (size_t)h*NT*4096 + lane*8;
    #define FRG(tt,kk,pp) (*(const bf16x8*)(wbase + (size_t)(tt)*4096 + (kk)*1024 + (pp)*512))

    for (int ks = 0; ks < 4; ++ks) {
        bf16x8 q0h = FRG(2*w,   ks, 0), q0l = FRG(2*w,   ks, 1);
        bf16x8 q1h = FRG(2*w+1, ks, 0), q1l = FRG(2*w+1, ks, 1);
        bf16x8 k0h = FRG(8+2*w,   ks, 0), k0l = FRG(8+2*w,   ks, 1);
        bf16x8 k1h = FRG(8+2*w+1, ks, 0), k1l = FRG(8+2*w+1, ks, 1);
        bf16x8 vth = FRG(16, ks, 0),      vtl = FRG(16, ks, 1);
        #pragma unroll
        for (int m = 0; m < 4; ++m) {
            const ushort* xp = xhi + (m*16 + c16)*XSTR + ks*32 + quad*8;
            bf16x8 ah = *(const bf16x8*)xp;
            bf16x8 al = *(const bf16x8*)(xp + 64*XSTR);
            aQ[m][0] = __builtin_amdgcn_mfma_f32_16x16x32_bf16(ah, q0h, aQ[m][0], 0,0,0);
            aQ[m][0] = __builtin_amdgcn_mfma_f32_16x16x32_bf16(ah, q0l, aQ[m][0], 0,0,0);
            aQ[m][0] = __builtin_amdgcn_mfma_f32_16x16x32_bf16(al, q0h, aQ[m][0], 0,0,0);
            aQ[m][1] = __builtin_amdgcn_mfma_f32_16x16x32_bf16(ah, q1h, aQ[m][1], 0,0,0);
            aQ[m][1] = __builtin_amdgcn_mfma_f32_16x16x32_bf16(ah, q1l, aQ[m][1], 0,0,0);
            aQ[m][1] = __builtin_amdgcn_mfma_f32_16x16x32_bf16(al, q1h, aQ[m][1], 0,0,0);
            aK[m][0] = __builtin_amdgcn_mfma_f32_16x16x32_bf16(ah, k0h, aK[m][0], 0,0,0);
            aK[m][0] = __builtin_amdgcn_mfma_f32_16x16x32_bf16(ah, k0l, aK[m][0], 0,0,0);
            aK[m][0] = __builtin_amdgcn_mfma_f32_16x16x32_bf16(al, k0h, aK[m][0], 0,0,0);
            aK[m][1] = __builtin_amdgcn_mfma_f32_16x16x32_bf16(ah, k1h, aK[m][1], 0,0,0);
            aK[m][1] = __builtin_amdgcn_mfma_f32_16x16x32_bf16(ah, k1l, aK[m][1], 0,0,0);
            aK[m][1] = __builtin_amdgcn_mfma_f32_16x16x32_bf16(al, k1h, aK[m][1], 0,0,0);
            if (m == w) {
                aV = __builtin_amdgcn_mfma_f32_16x16x32_bf16(ah, vth, aV, 0,0,0);
                aV = __builtin_amdgcn_mfma_f32_16x16x32_bf16(ah, vtl, aV, 0,0,0);
                aV = __builtin_amdgcn_mfma_f32_16x16x32_bf16(al, vth, aV, 0,0,0);
            }
        }
    }
    __syncthreads();   // x reads done; q/k frag panels overlay x region

    // ---- epilogue: bias + hi/lo split -> fragment-major panels (ks = w) ----
    //   value (l = mt*16+quad*4+r, e = w*32+nt*16+c16) -> panel (mt*4+w),
    //   blk = (nt*2 + (c16>>3))*16 + quad*4 + r, j = c16&7
    {
        const int jj = c16 & 7;
        const int blk0 = (c16 >> 3)*16 + quad*4;
        #pragma unroll
        for (int nt = 0; nt < 2; ++nt) {
            int e = w*32 + nt*16 + c16;
            float bQ = bq[h*DQKn + e];
            float bK = bk[h*DQKn + e];
            #pragma unroll
            for (int m = 0; m < 4; ++m) {
                int pbase = (m*4 + w)*512 + jj;
                #pragma unroll
                for (int r = 0; r < 4; ++r) {
                    int idx = pbase + (blk0 + nt*32 + r)*8;
                    float vq = aQ[m][nt][r] + bQ;
                    ushort qh_ = bf_hi(vq);
                    us[QH_OFF + idx] = qh_;
                    us[QL_OFF + idx] = bf_hi(vq - bf_f(qh_));
                    float vk = aK[m][nt][r] + bK;
                    ushort kh_ = bf_hi(vk);
                    us[KH_OFF + idx] = kh_;
                    us[KL_OFF + idx] = bf_hi(vk - bf_f(kh_));
                }
            }
        }
        float bV = bv[h*DVn + c16];
        #pragma unroll
        for (int r = 0; r < 4; ++r) {
            int mrow = w*16 + quad*4 + r;
            if (mrow < LL) sv[mrow*DVn + c16] = aV[r] + bV;
        }
    }
    __syncthreads();

    // ---- scores: S = Q K^T via MFMA (bf16x3). Wave w owns col tile w, mt=0..3 ----
    f32x4 sc[4];
    #pragma unroll
    for (int m = 0; m < 4; ++m) sc[m] = (f32x4){0.f,0.f,0.f,0.f};

    for (int ks = 0; ks < 4; ++ks) {
        bf16x8 kfh = *(const bf16x8*)(us + KH_OFF + (w*4 + ks)*512 + lane*8);
        bf16x8 kfl = *(const bf16x8*)(us + KL_OFF + (w*4 + ks)*512 + lane*8);
        #pragma unroll
        for (int mt = 0; mt < 4; ++mt) {
            bf16x8 qfh = *(const bf16x8*)(us + QH_OFF + (mt*4 + ks)*512 + lane*8);
            bf16x8 qfl = *(const bf16x8*)(us + QL_OFF + (mt*4 + ks)*512 + lane*8);
            sc[mt] = __builtin_amdgcn_mfma_f32_16x16x32_bf16(qfh, kfh, sc[mt], 0,0,0);
            sc[mt] = __builtin_amdgcn_mfma_f32_16x16x32_bf16(qfl, kfh, sc[mt], 0,0,0);
            sc[mt] = __builtin_amdgcn_mfma_f32_16x16x32_bf16(qfh, kfl, sc[mt], 0,0,0);
        }
    }

    // ---- leaky + column softmax (over l). Thread owns col m' = w*16+c16,
    //      rows l = mt*16 + quad*4 + r ; reduce local 16 + shfl over quad bits ----
    float mx = -INFINITY;
    #pragma unroll
    for (int mt = 0; mt < 4; ++mt)
        #pragma unroll
        for (int r = 0; r < 4; ++r) {
            float s = sc[mt][r];
            s = (s > 0.f) ? s : 0.1f*s;
            sc[mt][r] = s;
            int l = mt*16 + quad*4 + r;
            if (l < LL) mx = fmaxf(mx, s);
        }
    mx = fmaxf(mx, __shfl_xor(mx, 16));
    mx = fmaxf(mx, __shfl_xor(mx, 32));
    float sum = 0.f;
    #pragma unroll
    for (int mt = 0; mt < 4; ++mt)
        #pragma unroll
        for (int r = 0; r < 4; ++r) {
            int l = mt*16 + quad*4 + r;
            float p = (l < LL) ? __expf(sc[mt][r] - mx) : 0.f;
            sc[mt][r] = p;
            sum += p;
        }
    sum += __shfl_xor(sum, 16);
    sum += __shfl_xor(sum, 32);
    float inv = 1.0f / sum;

    __syncthreads();   // all q/k frag reads done; satt overlays
    #pragma unroll
    for (int mt = 0; mt < 4; ++mt)
        #pragma unroll
        for (int r = 0; r < 4; ++r)
            satt[(mt*16 + quad*4 + r)*SATT_STR + w*16 + c16] = sc[mt][r] * inv;
    __syncthreads();

    // ---- out[l, h*16+v] = relu( sum_m att[l][m] * V[m][v] ) ----
    const int lo = t >> 2;
    const int v0 = (t & 3) * 4;
    if (lo < LL) {
        float4 o = make_float4(0.f, 0.f, 0.f, 0.f);
        for (int m = 0; m < LL; ++m) {
            float  a  = satt[lo*SATT_STR + m];
            float4 vv = *(const float4*)(sv + m*DVn + v0);
            o.x += a*vv.x; o.y += a*vv.y; o.z += a*vv.z; o.w += a*vv.w;
        }
        o.x = fmaxf(o.x, 0.f); o.y = fmaxf(o.y, 0.f);
        o.z = fmaxf(o.z, 0.f); o.w = fmaxf(o.w, 0.f);
        *(float4*)(out + (size_t)b*(LL*FF) + lo*FF + h*DVn + v0) = o;
    }
}

extern "C" void kernel_launch(void* const* d_in, const int* in_sizes, int n_in,
                              void* d_out, int out_size, void* d_ws, size_t ws_size,
                              hipStream_t stream)
{
    const float* hid = (const float*)d_in[0];
    const float* Wq  = (const float*)d_in[1];
    const float* bq  = (const float*)d_in[2];
    const float* Wk  = (const float*)d_in[3];
    const float* bk  = (const float*)d_in[4];
    const float* Wv  = (const float*)d_in[5];
    const float* bv  = (const float*)d_in[6];
    float* o    = (float*)d_out;
    ushort* wp  = (ushort*)d_ws;   // 1.06 MiB

    pack_w<<<dim3(136), dim3(256), 0, stream>>>(Wq, Wk, Wv, wp);
    attn_fused<<<dim3(NB*HH), dim3(256), 0, stream>>>(hid, wp, bq, bk, bv, o);
}

// Round 4
// 791.393 us; speedup vs baseline: 7.1610x; 1.1764x over previous
//
#include <hip/hip_runtime.h>
#include <math.h>

#define NB   4096
#define LL   50
#define FF   128
#define HH   8
#define DVn  16

typedef __attribute__((ext_vector_type(8))) short bf16x8;
typedef __attribute__((ext_vector_type(4))) float f32x4;

__device__ __forceinline__ ushort bf_hi(float x) {
    uint u = __float_as_uint(x);
    uint r = u + 0x7FFFu + ((u >> 16) & 1u);   // RTNE to bf16
    return (ushort)(r >> 16);
}
__device__ __forceinline__ float bf_f(ushort b) { return __uint_as_float(((uint)b) << 16); }

// ---------------- pack: M = Wq Wk^T, u = Wq bk, v = Wk bq, c = bq.bk, Wv ----
// wp frag layout per head: tiles 0..7 = M n-cols, 8 = [u|v|0..], 9 = Wv.
//   tile stride 4096 u, ks stride 1024, part(hi/lo) stride 512, lane*8.
//   B[k][n]: n = lane&15, k = (lane>>4)*8 + j, f = ks*32 + k, n-col = tile*16 + (lane&15)
// c[] floats at ushort offset 327680.
__global__ void pack_w(const float* __restrict__ Wq, const float* __restrict__ bq,
                       const float* __restrict__ Wk, const float* __restrict__ bk,
                       const float* __restrict__ Wv, ushort* __restrict__ wp)
{
    int id = blockIdx.x * 256 + threadIdx.x;       // 8*10*4*64 = 20480
    if (id >= HH*10*4*64) return;
    int lane = id & 63;
    int ks   = (id >> 6) & 3;
    int ht   = id >> 8;
    int tile = ht % 10;
    int h    = ht / 10;
    int c    = lane & 15;
    int f0   = ks*32 + (lane >> 4)*8;

    float val[8];
    #pragma unroll
    for (int j = 0; j < 8; ++j) val[j] = 0.f;

    if (tile < 8) {                                 // M[f][g] = sum_e Wq[f][e] Wk[g][e]
        const float* wq = Wq + (size_t)h*FF*FF;
        const float* wk = Wk + (size_t)h*FF*FF;
        int g = tile*16 + c;
        for (int e = 0; e < FF; ++e) {
            float kv = wk[(size_t)g*FF + e];
            #pragma unroll
            for (int j = 0; j < 8; ++j)
                val[j] += wq[(size_t)(f0+j)*FF + e] * kv;
        }
    } else if (tile == 8) {                         // col0 = u = Wq bk, col1 = v = Wk bq
        if (c == 0) {
            const float* wq = Wq + (size_t)h*FF*FF;
            for (int e = 0; e < FF; ++e) {
                float bb = bk[h*FF + e];
                #pragma unroll
                for (int j = 0; j < 8; ++j) val[j] += wq[(size_t)(f0+j)*FF + e] * bb;
            }
        } else if (c == 1) {
            const float* wk = Wk + (size_t)h*FF*FF;
            for (int e = 0; e < FF; ++e) {
                float bb = bq[h*FF + e];
                #pragma unroll
                for (int j = 0; j < 8; ++j) val[j] += wk[(size_t)(f0+j)*FF + e] * bb;
            }
        }
        if (ks == 0 && lane == 2) {                 // c = bq.bk once per head
            float s = 0.f;
            for (int e = 0; e < FF; ++e) s += bq[h*FF+e] * bk[h*FF+e];
            ((float*)(wp + 327680))[h] = s;
        }
    } else {                                        // Wv B-frag
        const float* wv = Wv + (size_t)h*FF*DVn;
        #pragma unroll
        for (int j = 0; j < 8; ++j) val[j] = wv[(size_t)(f0+j)*DVn + c];
    }

    ushort hi[8], lo[8];
    #pragma unroll
    for (int j = 0; j < 8; ++j) {
        ushort hb = bf_hi(val[j]);
        hi[j] = hb;
        lo[j] = bf_hi(val[j] - bf_f(hb));
    }
    size_t base = (size_t)h*40960 + (size_t)tile*4096 + ks*1024 + lane*8;
    *(ushort4*)(wp + base)       = make_ushort4(hi[0],hi[1],hi[2],hi[3]);
    *(ushort4*)(wp + base + 4)   = make_ushort4(hi[4],hi[5],hi[6],hi[7]);
    *(ushort4*)(wp + base + 512) = make_ushort4(lo[0],lo[1],lo[2],lo[3]);
    *(ushort4*)(wp + base + 516) = make_ushort4(lo[4],lo[5],lo[6],lo[7]);
}

// ---------------- fused attention ----------------
// LDS (ushorts; 80384 B total -> 2 blocks/CU):
//   xh panels [mt4][ks4] @0, xl @8448    (panel stride 528: 264 dw == 8 mod 32)
//   th @16896, tl @25344  (T hi/lo frag panels)
//   vf @33792 (2 ks panels x 512, V B-frag bf16, hi only)
//   satt bf16 [64][80] @34816
//   tu[64],tv[64] fp32 @float 19968/20032
#define PX    528
#define XH0   0
#define XL0   8448
#define TH0   16896
#define TL0   25344
#define VF0   33792
#define SATT0 34816
#define TU0   19968
#define TV0   20032
#define LDS_FLOATS 20096

__global__ __launch_bounds__(256, 2)
void attn_fused(const float* __restrict__ hid, const ushort* __restrict__ wp,
                const float* __restrict__ ccp, const float* __restrict__ bv,
                float* __restrict__ out)
{
    __shared__ __align__(16) float lds[LDS_FLOATS];
    ushort* us = (ushort*)lds;
    float*  tu = lds + TU0;
    float*  tv = lds + TV0;

    const int t    = threadIdx.x;
    const int b    = blockIdx.x >> 3;
    const int h    = blockIdx.x & 7;
    const int lane = t & 63;
    const int w    = t >> 6;
    const int c16  = lane & 15;
    const int quad = lane >> 4;

    // ---- stage x -> bf16 hi/lo A-frag panels (pad rows garbage; masked later) ----
    {
        const float4* src = (const float4*)(hid + (size_t)b * (LL*FF));
        for (int i = t; i < 1600; i += 256) {
            float4 v = src[i];
            int l = i >> 5, f0 = (i & 31) * 4;
            int slot = ((l>>4)*4 + (f0>>5))*PX + ((l&15) + 16*((f0&31)>>3))*8 + (f0&7);
            ushort4 hv, lv;
            hv.x = bf_hi(v.x); lv.x = bf_hi(v.x - bf_f(hv.x));
            hv.y = bf_hi(v.y); lv.y = bf_hi(v.y - bf_f(hv.y));
            hv.z = bf_hi(v.z); lv.z = bf_hi(v.z - bf_f(hv.z));
            hv.w = bf_hi(v.w); lv.w = bf_hi(v.w - bf_f(hv.w));
            *(ushort4*)(us + XH0 + slot) = hv;
            *(ushort4*)(us + XL0 + slot) = lv;
        }
    }
    __syncthreads();

    // ---- T = x.[M|u|v], V = x.Wv  (bf16x3 / x1 / x2). Wave w: n-tiles {2w,2w+1} ----
    f32x4 aT[4][2], aU, aV;
    #pragma unroll
    for (int m = 0; m < 4; ++m) {
        aT[m][0] = (f32x4){0.f,0.f,0.f,0.f};
        aT[m][1] = (f32x4){0.f,0.f,0.f,0.f};
    }
    aU = (f32x4){0.f,0.f,0.f,0.f};
    aV = (f32x4){0.f,0.f,0.f,0.f};

    const ushort* wb = wp + (size_t)h*40960 + lane*8;
    #define WFRG(tt,kk,pp) (*(const bf16x8*)(wb + (size_t)(tt)*4096 + (kk)*1024 + (pp)*512))

    for (int ks = 0; ks < 4; ++ks) {
        bf16x8 m0h = WFRG(2*w,   ks, 0), m0l = WFRG(2*w,   ks, 1);
        bf16x8 m1h = WFRG(2*w+1, ks, 0), m1l = WFRG(2*w+1, ks, 1);
        bf16x8 uvh = WFRG(8, ks, 0);
        bf16x8 vvh = WFRG(9, ks, 0);
        #pragma unroll
        for (int mt = 0; mt < 4; ++mt) {
            const ushort* xp = us + XH0 + (mt*4 + ks)*PX + lane*8;
            bf16x8 ah = *(const bf16x8*)xp;
            bf16x8 al = *(const bf16x8*)(xp + XL0);
            aT[mt][0] = __builtin_amdgcn_mfma_f32_16x16x32_bf16(ah, m0h, aT[mt][0], 0,0,0);
            aT[mt][0] = __builtin_amdgcn_mfma_f32_16x16x32_bf16(ah, m0l, aT[mt][0], 0,0,0);
            aT[mt][0] = __builtin_amdgcn_mfma_f32_16x16x32_bf16(al, m0h, aT[mt][0], 0,0,0);
            aT[mt][1] = __builtin_amdgcn_mfma_f32_16x16x32_bf16(ah, m1h, aT[mt][1], 0,0,0);
            aT[mt][1] = __builtin_amdgcn_mfma_f32_16x16x32_bf16(ah, m1l, aT[mt][1], 0,0,0);
            aT[mt][1] = __builtin_amdgcn_mfma_f32_16x16x32_bf16(al, m1h, aT[mt][1], 0,0,0);
            if (mt == w) {
                aU = __builtin_amdgcn_mfma_f32_16x16x32_bf16(ah, uvh, aU, 0,0,0);
                aV = __builtin_amdgcn_mfma_f32_16x16x32_bf16(ah, vvh, aV, 0,0,0);
                aV = __builtin_amdgcn_mfma_f32_16x16x32_bf16(al, vvh, aV, 0,0,0);
            }
        }
    }
    __syncthreads();

    // ---- epilogue: T -> hi/lo frag panels (ks = w); tu/tv; V B-frag ----
    {
        const int jj   = c16 & 7;
        const int blk0 = (c16 >> 3)*16 + quad*4;
        #pragma unroll
        for (int nt = 0; nt < 2; ++nt) {
            #pragma unroll
            for (int mt = 0; mt < 4; ++mt) {
                int pb = (mt*4 + w)*PX + jj;
                #pragma unroll
                for (int r = 0; r < 4; ++r) {
                    int idx = pb + (blk0 + nt*32 + r)*8;
                    float tval = aT[mt][nt][r];
                    ushort th_ = bf_hi(tval);
                    us[TH0 + idx] = th_;
                    us[TL0 + idx] = bf_hi(tval - bf_f(th_));
                }
            }
        }
        if (c16 < 2) {
            float* dst = (c16 == 0) ? tu : tv;
            #pragma unroll
            for (int r = 0; r < 4; ++r) dst[w*16 + quad*4 + r] = aU[r];
        }
        float bvv = bv[h*DVn + c16];
        int ksp = w >> 1;
        #pragma unroll
        for (int r = 0; r < 4; ++r) {
            int m  = w*16 + quad*4 + r;
            int mm = (w&1)*16 + quad*4 + r;
            int Lp = c16 + 16*(mm >> 3);
            us[VF0 + ksp*512 + Lp*8 + (mm & 7)] = (m < LL) ? bf_hi(aV[r] + bvv) : (ushort)0;
        }
    }
    __syncthreads();

    // ---- scores: S = T x^T (bf16x3). Wave w: col tile w (B = x panels [w][ks]) ----
    f32x4 sc[4];
    #pragma unroll
    for (int m = 0; m < 4; ++m) sc[m] = (f32x4){0.f,0.f,0.f,0.f};

    for (int ks = 0; ks < 4; ++ks) {
        const ushort* xb = us + XH0 + (w*4 + ks)*PX + lane*8;
        bf16x8 bh = *(const bf16x8*)xb;
        bf16x8 bl = *(const bf16x8*)(xb + XL0);
        #pragma unroll
        for (int mt = 0; mt < 4; ++mt) {
            const ushort* tb = us + TH0 + (mt*4 + ks)*PX + lane*8;
            bf16x8 th = *(const bf16x8*)tb;
            bf16x8 tl = *(const bf16x8*)(tb + XL0);   // TL0-TH0 == XL0
            sc[mt] = __builtin_amdgcn_mfma_f32_16x16x32_bf16(th, bh, sc[mt], 0,0,0);
            sc[mt] = __builtin_amdgcn_mfma_f32_16x16x32_bf16(tl, bh, sc[mt], 0,0,0);
            sc[mt] = __builtin_amdgcn_mfma_f32_16x16x32_bf16(th, bl, sc[mt], 0,0,0);
        }
    }

    // ---- add rank-1/const terms, leaky, column softmax (over l) ----
    const float cc  = ccp[h];
    const int mcol  = w*16 + c16;
    const float tvv = tv[mcol] + cc;
    float mx = -INFINITY;
    #pragma unroll
    for (int mt = 0; mt < 4; ++mt)
        #pragma unroll
        for (int r = 0; r < 4; ++r) {
            int l = mt*16 + quad*4 + r;
            float s = sc[mt][r] + tu[l] + tvv;
            s = (s > 0.f) ? s : 0.1f*s;
            sc[mt][r] = s;
            if (l < LL) mx = fmaxf(mx, s);
        }
    mx = fmaxf(mx, __shfl_xor(mx, 16));
    mx = fmaxf(mx, __shfl_xor(mx, 32));
    float sum = 0.f;
    #pragma unroll
    for (int mt = 0; mt < 4; ++mt)
        #pragma unroll
        for (int r = 0; r < 4; ++r) {
            int l = mt*16 + quad*4 + r;
            float p = (l < LL) ? __expf(sc[mt][r] - mx) : 0.f;
            sc[mt][r] = p;
            sum += p;
        }
    sum += __shfl_xor(sum, 16);
    sum += __shfl_xor(sum, 32);
    float inv = 1.0f / sum;

    // satt bf16 [64][80]; cols >=50 zeroed (keeps NaN out of PV)
    #pragma unroll
    for (int mt = 0; mt < 4; ++mt)
        #pragma unroll
        for (int r = 0; r < 4; ++r) {
            int l = mt*16 + quad*4 + r;
            us[SATT0 + l*80 + mcol] = (mcol < LL) ? bf_hi(sc[mt][r] * inv) : (ushort)0;
        }
    __syncthreads();

    // ---- out = relu(att.V) via MFMA; wave w owns l-tile w ----
    f32x4 ao = (f32x4){0.f,0.f,0.f,0.f};
    #pragma unroll
    for (int ksp = 0; ksp < 2; ++ksp) {
        bf16x8 af = *(const bf16x8*)(us + SATT0 + (w*16 + c16)*80 + ksp*32 + quad*8);
        bf16x8 bf = *(const bf16x8*)(us + VF0 + ksp*512 + lane*8);
        ao = __builtin_amdgcn_mfma_f32_16x16x32_bf16(af, bf, ao, 0,0,0);
    }
    #pragma unroll
    for (int r = 0; r < 4; ++r) {
        int l = w*16 + quad*4 + r;
        if (l < LL)
            out[(size_t)b*(LL*FF) + l*FF + h*DVn + c16] = fmaxf(ao[r], 0.f);
    }
}

extern "C" void kernel_launch(void* const* d_in, const int* in_sizes, int n_in,
                              void* d_out, int out_size, void* d_ws, size_t ws_size,
                              hipStream_t stream)
{
    const float* hid = (const float*)d_in[0];
    const float* Wq  = (const float*)d_in[1];
    const float* bq  = (const float*)d_in[2];
    const float* Wk  = (const float*)d_in[3];
    const float* bk  = (const float*)d_in[4];
    const float* Wv  = (const float*)d_in[5];
    const float* bv  = (const float*)d_in[6];
    float* o    = (float*)d_out;
    ushort* wp  = (ushort*)d_ws;                       // 655392 B used
    const float* ccp = (const float*)(wp + 327680);

    pack_w<<<dim3(80), dim3(256), 0, stream>>>(Wq, bq, Wk, bk, Wv, wp);
    attn_fused<<<dim3(NB*HH), dim3(256), 0, stream>>>(hid, wp, ccp, bv, o);
}